// Round 1
// 396.271 us; speedup vs baseline: 1.0891x; 1.0891x over previous
//
#include <hip/hip_runtime.h>
#include <math.h>

#define BATCH 4
#define CIN   512
#define PABN  64
#define HW    4096
#define PROW  4356            // 66*66 padded pixel rows

typedef __attribute__((ext_vector_type(8))) short bfrag;   // 8 bf16
typedef __attribute__((ext_vector_type(4))) float ffrag;   // 4 fp32
#define MFMA(a, b, c) __builtin_amdgcn_mfma_f32_16x16x32_bf16(a, b, c, 0, 0, 0)

__device__ __forceinline__ void gload16(const void* g, void* l) {
    __builtin_amdgcn_global_load_lds(
        (const __attribute__((address_space(1))) unsigned int*)g,
        (__attribute__((address_space(3))) unsigned int*)l, 16, 0, 0);
}

__device__ __forceinline__ unsigned f2bf(float f) {   // fp32 -> bf16 bits, RNE
    unsigned u = __float_as_uint(f);
    return (u + 0x7fffu + ((u >> 16) & 1u)) >> 16;
}

// padded row index for pixel n: (h+1)*66 + (w+1) = n + 2*(n>>6) + 67
__device__ __forceinline__ int prow(int n) { return n + 2 * (n >> 6) + 67; }

// ---------------------------------------------------------------------------
__global__ __launch_bounds__(256) void k_fill0(uint4* __restrict__ p) {
    uint4 z; z.x = z.y = z.z = z.w = 0u;
    p[(size_t)blockIdx.x * 256 + threadIdx.x] = z;
}

// w_top/w_cen [64][512] fp32 -> bf16 (layout kept: [p][i], K=i contiguous)
__global__ __launch_bounds__(256) void k_wpc(const float* __restrict__ wt,
        const float* __restrict__ wc, short* __restrict__ ot, short* __restrict__ oc) {
    const float* src = blockIdx.y ? wc : wt;
    short* dst       = blockIdx.y ? oc : ot;
    int idx = (blockIdx.x * 256 + threadIdx.x) * 4;
    float4 v = *(const float4*)(src + idx);
    uint2 u;
    u.x = f2bf(v.x) | (f2bf(v.y) << 16);
    u.y = f2bf(v.z) | (f2bf(v.w) << 16);
    *(uint2*)(dst + idx) = u;
}

// w [O][I][3][3] fp32 -> wT[k][o][i] bf16
__global__ __launch_bounds__(256) void k_w9(const float* __restrict__ wb,
        const float* __restrict__ wo, short* __restrict__ wbT, short* __restrict__ woT) {
    const float* w = blockIdx.z ? wo : wb;
    short* wT      = blockIdx.z ? woT : wbT;
    int o = blockIdx.x;
    int i = blockIdx.y * 256 + threadIdx.x;
    const float* src = w + ((size_t)o * CIN + i) * 9;
    float v[9];
#pragma unroll
    for (int k = 0; k < 9; k++) v[k] = src[k];
#pragma unroll
    for (int k = 0; k < 9; k++)
        wT[((size_t)k * CIN + o) * CIN + i] = (short)f2bf(v[k]);
}

// ---------------------------------------------------------------------------
// x [B][512][4096] fp32 (ADD: + invZ * O [n][c] fp32, raw-reshape-equivalent) ->
// pixel-major padded bf16 xp [B][4356][512]. Borders pre-zeroed by k_fill0.
// grid (64 pix-tiles, 8 ch-tiles, B)
template <bool ADD>
__global__ __launch_bounds__(256) void k_padT(const float* __restrict__ x,
        const float* __restrict__ Oc, const float* __restrict__ Zp,
        short* __restrict__ xp) {
    __shared__ float Ts[64][68];
    int t = threadIdx.x;
    int n0 = blockIdx.x * 64, c0 = blockIdx.y * 64, b = blockIdx.z;
    float iz = ADD ? (1.0f / Zp[b]) : 1.0f;
    const float* xb = x + ((size_t)b * CIN + c0) * HW;
#pragma unroll
    for (int j = 0; j < 4; j++) {
        int slot = j * 256 + t;
        int r = slot >> 4, col = (slot & 15) * 4;
        float4 v = *(const float4*)(xb + (size_t)r * HW + n0 + col);
        *(float4*)&Ts[r][col] = v;
    }
    __syncthreads();
    short* xpb = xp + (size_t)b * PROW * CIN;
    const float* ob = ADD ? (Oc + (size_t)b * HW * CIN) : nullptr;
#pragma unroll
    for (int j = 0; j < 2; j++) {
        int slot = j * 256 + t;
        int pix = slot >> 3, ch = (slot & 7) * 8;
        int rp = prow(n0 + pix);
        float v[8];
#pragma unroll
        for (int k = 0; k < 8; k++) v[k] = Ts[ch + k][pix];
        if (ADD) {
            const float* os = ob + (size_t)(n0 + pix) * CIN + c0 + ch;
#pragma unroll
            for (int k = 0; k < 8; k += 4) {
                float4 o4 = *(const float4*)(os + k);
                v[k]   += o4.x * iz; v[k+1] += o4.y * iz;
                v[k+2] += o4.z * iz; v[k+3] += o4.w * iz;
            }
        }
        unsigned pk[4];
#pragma unroll
        for (int k = 0; k < 4; k++)
            pk[k] = f2bf(v[2*k]) | (f2bf(v[2*k+1]) << 16);
        *(uint4*)(xpb + (size_t)rp * CIN + c0 + ch) = *(uint4*)pk;
    }
}

// ---------------------------------------------------------------------------
// 1x1 convs: xt/xc[n][p] = sum_i xp[n][i]*w[p][i] + bias.  M=p(64), N=n(64), K=512
// grid (64 n-tiles, 8: b*2+which)
__global__ __launch_bounds__(256) void k_qk(const short* __restrict__ xp,
        const short* __restrict__ wtop, const short* __restrict__ wcen,
        const float* __restrict__ btop, const float* __restrict__ bcen,
        short* __restrict__ xt, short* __restrict__ xc) {
    __shared__ __align__(16) short As[2048];   // w: 64 rows(p) x 32(i)
    __shared__ __align__(16) short Bs[2048];   // x: 64 rows(n) x 32(i)
    int t = threadIdx.x;
    int n0 = blockIdx.x * 64;
    int b = blockIdx.y >> 1, which = blockIdx.y & 1;
    const short* w    = which ? wcen : wtop;
    const float* bias = which ? bcen : btop;
    short* out        = (which ? xc : xt) + (size_t)b * HW * PABN;
    const short* xb   = xp + (size_t)b * PROW * CIN;

    int arow = t >> 2, ach = t & 3;
    int sch = ach ^ ((arow >> 1) & 3);
    int rp = prow(n0 + arow);
    int lane = t & 63, wid = t >> 6, l15 = lane & 15, q = lane >> 4;
    int wm = wid >> 1, wn = wid & 1;
    int cx = (q ^ ((l15 >> 1) & 3)) * 8;
    ffrag acc[2][2] = {};

    for (int i0 = 0; i0 < CIN; i0 += 32) {
        gload16(w  + (size_t)arow * CIN + i0 + sch * 8, As + t * 8);
        gload16(xb + (size_t)rp   * CIN + i0 + sch * 8, Bs + t * 8);
        __syncthreads();
        bfrag a[2], bb[2];
        a[0]  = *(const bfrag*)(As + (wm * 32 + l15) * 32 + cx);
        a[1]  = *(const bfrag*)(As + (wm * 32 + 16 + l15) * 32 + cx);
        bb[0] = *(const bfrag*)(Bs + (wn * 32 + l15) * 32 + cx);
        bb[1] = *(const bfrag*)(Bs + (wn * 32 + 16 + l15) * 32 + cx);
        acc[0][0] = MFMA(a[0], bb[0], acc[0][0]);
        acc[0][1] = MFMA(a[0], bb[1], acc[0][1]);
        acc[1][0] = MFMA(a[1], bb[0], acc[1][0]);
        acc[1][1] = MFMA(a[1], bb[1], acc[1][1]);
        __syncthreads();
    }
#pragma unroll
    for (int mi = 0; mi < 2; mi++) {
        int p = wm * 32 + mi * 16 + q * 4;
        float4 bv = *(const float4*)(bias + p);
#pragma unroll
        for (int ni = 0; ni < 2; ni++) {
            int nn = n0 + wn * 32 + ni * 16 + l15;
            ffrag v = acc[mi][ni];
            uint2 u;
            u.x = f2bf(v.x + bv.x) | (f2bf(v.y + bv.y) << 16);
            u.y = f2bf(v.z + bv.z) | (f2bf(v.w + bv.w) << 16);
            *(uint2*)(out + (size_t)nn * PABN + p) = u;
        }
    }
}

// ---------------------------------------------------------------------------
// conv3x3: out = conv(in, wT) + bias.  M=n(128), N=o(128), K=i over 9 taps.
// BK=64: LDS rows 64 shorts (128B), 8 chunks: swizzle chunk ^ (row&7).
// grid (32 n-tiles, 4 o-tiles, B)
template <bool FP32OUT>
__global__ __launch_bounds__(256) void k_conv(const short* __restrict__ xin,
        const short* __restrict__ wT, const float* __restrict__ bias,
        void* __restrict__ outv) {
    __shared__ __align__(16) short As[8192];   // pixels: 128 x 64
    __shared__ __align__(16) short Bs[8192];   // weights: 128(o) x 64
    int t = threadIdx.x;
    int n0 = blockIdx.x * 128, o0 = blockIdx.y * 128, b = blockIdx.z;
    const short* xb = xin + (size_t)b * PROW * CIN;
    int lane = t & 63, wid = t >> 6, l15 = lane & 15, q = lane >> 4;
    int wm = wid >> 1, wn = wid & 1;
    int arow = t >> 3, ach = t & 7;
    int sch = ach ^ (arow & 7);
    int pr[4];
#pragma unroll
    for (int j = 0; j < 4; j++) pr[j] = prow(n0 + j * 32 + arow);
    ffrag acc[4][4] = {};

    for (int k9 = 0; k9 < 9; k9++) {
        int kh = k9 / 3, kw = k9 - kh * 3;
        int sh = (kh - 1) * 66 + (kw - 1);
        const short* wk = wT + (size_t)k9 * CIN * CIN;
        for (int i0 = 0; i0 < CIN; i0 += 64) {
#pragma unroll
            for (int j = 0; j < 4; j++) {
                gload16(xb + (size_t)(pr[j] + sh) * CIN + i0 + sch * 8,
                        As + (j * 256 + t) * 8);
                gload16(wk + (size_t)(o0 + j * 32 + arow) * CIN + i0 + sch * 8,
                        Bs + (j * 256 + t) * 8);
            }
            __syncthreads();
#pragma unroll
            for (int kc = 0; kc < 2; kc++) {
                int cx = (((kc * 4 + q) ^ (l15 & 7))) * 8;
                bfrag a[4], bb[4];
#pragma unroll
                for (int mi = 0; mi < 4; mi++)
                    a[mi] = *(const bfrag*)(As + (wm * 64 + mi * 16 + l15) * 64 + cx);
#pragma unroll
                for (int ni = 0; ni < 4; ni++)
                    bb[ni] = *(const bfrag*)(Bs + (wn * 64 + ni * 16 + l15) * 64 + cx);
#pragma unroll
                for (int mi = 0; mi < 4; mi++)
#pragma unroll
                    for (int ni = 0; ni < 4; ni++)
                        acc[mi][ni] = MFMA(a[mi], bb[ni], acc[mi][ni]);
            }
            __syncthreads();
        }
    }
#pragma unroll
    for (int ni = 0; ni < 4; ni++) {
        int o = o0 + wn * 64 + ni * 16 + l15;
        float bv = bias[o];
#pragma unroll
        for (int mi = 0; mi < 4; mi++) {
            int n = n0 + wm * 64 + mi * 16 + q * 4;
            ffrag v = acc[mi][ni];
            if (FP32OUT) {
                float* out = (float*)outv + (size_t)b * CIN * HW;
                *(float4*)(out + (size_t)o * HW + n) =
                    make_float4(v.x + bv, v.y + bv, v.z + bv, v.w + bv);
            } else {
                short* out = (short*)outv + (size_t)b * CIN * HW;
                uint2 u;
                u.x = f2bf(v.x + bv) | (f2bf(v.y + bv) << 16);
                u.y = f2bf(v.z + bv) | (f2bf(v.w + bv) << 16);
                *(uint2*)(out + (size_t)o * HW + n) = u;
            }
        }
    }
}

// ---------------------------------------------------------------------------
// Fused S+PV (flash-style, global softmax => no rescale):
//   per block: n-tile 128, c-half 256, one batch. Loop m over 4096 in steps of 64:
//     S[128n][64m] = xc.xt^T (K=64) -> exp -> P in LDS (chunk-swizzled)
//     O[c][n] += xb[c][m-tile] . P^T   (acc in VGPR, unscaled; invZ applied in k_padT)
//   Zbuf[b*32+ntile] = sum exp (only c-half 0 blocks).
// 8 waves (512 thr), 1 block/CU, grid 256 XCD-swizzled. LDS 112 KB:
//   XC[128][64] persistent | XT[2][64][64] dbuf | XB[2][256][64] dbuf | PS[128][64]
// Raw s_barrier + counted vmcnt keeps 5 staging loads in flight across barriers.
__global__ __launch_bounds__(512) void k_fused(const short* __restrict__ xc,
        const short* __restrict__ xt, const short* __restrict__ xb,
        float* __restrict__ O, float* __restrict__ Zbuf) {
    __shared__ __align__(16) short SM[57344];   // 112 KB
    __shared__ float red[8];
    short* XC  = SM;                 // [128][64]
    short* XT0 = SM + 8192;          // [2][64][64]
    short* XB0 = SM + 16384;         // [2][256][64]
    short* PS  = SM + 49152;         // [128][64]

    int wg = ((blockIdx.x & 7) << 5) | (blockIdx.x >> 3);   // XCD-contiguous
    int b = wg >> 6, chalf = (wg >> 5) & 1, ntile = wg & 31;
    int n0 = ntile * 128, c0 = chalf * 256;
    const short* xcb = xc + (size_t)b * HW * PABN;
    const short* xtb = xt + (size_t)b * HW * PABN;
    const short* xbb = xb + (size_t)b * CIN * HW;

    int t = threadIdx.x;
    int lane = t & 63, wid = t >> 6, l15 = lane & 15, q = lane >> 4;
    int srow = t >> 3, sch = (t & 7) ^ (srow & 7);   // staging row / swizzled chunk
    int wc = wid >> 1, wnn = wid & 1;                // PV wave roles: c-quarter, n-half

    // prologue: persistent xc tile + step-0 xt/xb
    {
        const short* s0 = xcb + (size_t)(n0 + srow) * PABN + sch * 8;
        gload16(s0, XC + t * 8);
        gload16(s0 + 64 * PABN, XC + 4096 + t * 8);
        gload16(xtb + (size_t)srow * PABN + sch * 8, XT0 + t * 8);
#pragma unroll
        for (int p = 0; p < 4; p++)
            gload16(xbb + (size_t)(c0 + p * 64 + srow) * HW + sch * 8,
                    XB0 + (p * 512 + t) * 8);
    }
    asm volatile("s_waitcnt vmcnt(0)" ::: "memory");
    __builtin_amdgcn_s_barrier();
    asm volatile("" ::: "memory");

    // xc A-fragments are loop-invariant: hoist (wave wid owns S rows [wid*16,+16))
    bfrag aS[2];
#pragma unroll
    for (int kc = 0; kc < 2; kc++)
        aS[kc] = *(const bfrag*)(XC + (wid * 16 + l15) * 64
                                 + ((kc * 4 + q) ^ (l15 & 7)) * 8);

    ffrag acc[4][4] = {};
    float zacc = 0.f;

    for (int it = 0; it < 64; ++it) {
        int cur = it & 1;
        const short* XTc = XT0 + cur * 4096;
        const short* XBc = XB0 + cur * 16384;
        if (it < 63) {                       // issue next-step staging, keep in flight
            int m1 = (it + 1) * 64, nxt = cur ^ 1;
            gload16(xtb + (size_t)(m1 + srow) * PABN + sch * 8,
                    XT0 + nxt * 4096 + t * 8);
#pragma unroll
            for (int p = 0; p < 4; p++)
                gload16(xbb + (size_t)(c0 + p * 64 + srow) * HW + m1 + sch * 8,
                        XB0 + nxt * 16384 + (p * 512 + t) * 8);
            asm volatile("s_waitcnt vmcnt(5)" ::: "memory");   // wait prev group only
        } else {
            asm volatile("s_waitcnt vmcnt(0)" ::: "memory");
        }
        __builtin_amdgcn_s_barrier();
        asm volatile("" ::: "memory");

        // ---- S phase: wave wid computes S rows [wid*16,+16) x m[0,64)
        ffrag s[4] = {};
        __builtin_amdgcn_s_setprio(1);
#pragma unroll
        for (int ni = 0; ni < 4; ni++)
#pragma unroll
            for (int kc = 0; kc < 2; kc++) {
                bfrag bf = *(const bfrag*)(XTc + (ni * 16 + l15) * 64
                                           + ((kc * 4 + q) ^ (l15 & 7)) * 8);
                s[ni] = MFMA(aS[kc], bf, s[ni]);
            }
        __builtin_amdgcn_s_setprio(0);
        // exp + write P (bf16) chunk-swizzled: logical chunk cc at pos cc^(row&7)
        int nrow = wid * 16 + q * 4;
#pragma unroll
        for (int ni = 0; ni < 4; ni++) {
            int cc = ni * 2 + (l15 >> 3), j = l15 & 7;
#pragma unroll
            for (int r = 0; r < 4; r++) {
                float e = __expf(s[ni][r]);
                zacc += e;
                PS[(nrow + r) * 64 + (cc ^ ((nrow + r) & 7)) * 8 + j] =
                    (short)f2bf(e);
            }
        }
        asm volatile("s_waitcnt lgkmcnt(0)" ::: "memory");
        __builtin_amdgcn_s_barrier();
        asm volatile("" ::: "memory");

        // ---- PV phase: acc[c][n] += xb . P^T  (wave: c 64 x n 64)
        __builtin_amdgcn_s_setprio(1);
#pragma unroll
        for (int kc = 0; kc < 2; kc++) {
            int cx = ((kc * 4 + q) ^ (l15 & 7)) * 8;
            bfrag av[4], bv[4];
#pragma unroll
            for (int ci = 0; ci < 4; ci++)
                av[ci] = *(const bfrag*)(XBc + (wc * 64 + ci * 16 + l15) * 64 + cx);
#pragma unroll
            for (int nj = 0; nj < 4; nj++)
                bv[nj] = *(const bfrag*)(PS + (wnn * 64 + nj * 16 + l15) * 64 + cx);
#pragma unroll
            for (int ci = 0; ci < 4; ci++)
#pragma unroll
                for (int nj = 0; nj < 4; nj++)
                    acc[ci][nj] = MFMA(av[ci], bv[nj], acc[ci][nj]);
        }
        __builtin_amdgcn_s_setprio(0);
        asm volatile("" ::: "memory");
        __builtin_amdgcn_s_barrier();
        asm volatile("" ::: "memory");
    }

    // ---- z reduce (c-half 0 only contributes; both halves computed same S)
#pragma unroll
    for (int off = 32; off > 0; off >>= 1) zacc += __shfl_down(zacc, off, 64);
    if (lane == 0) red[wid] = zacc;
    __syncthreads();
    if (chalf == 0 && t == 0) {
        float z = 0.f;
#pragma unroll
        for (int i = 0; i < 8; i++) z += red[i];
        Zbuf[b * 32 + ntile] = z;
    }
    // ---- O store (unscaled fp32, [n][c])
    float* Ob = O + (size_t)b * HW * CIN;
#pragma unroll
    for (int ci = 0; ci < 4; ci++)
#pragma unroll
        for (int nj = 0; nj < 4; nj++) {
            int n = n0 + wnn * 64 + nj * 16 + l15;
            int c = c0 + wc * 64 + ci * 16 + q * 4;
            ffrag v = acc[ci][nj];
            *(float4*)(Ob + (size_t)n * CIN + c) =
                make_float4(v.x, v.y, v.z, v.w);
        }
}

// ---------------------------------------------------------------------------
// Reduce Zbuf[b][0..31] -> Z[b]. 1 block, 256 thr (wave per batch).
__global__ __launch_bounds__(256) void k_redz(const float* __restrict__ Zbuf,
        float* __restrict__ Z) {
    int wid = threadIdx.x >> 6, lane = threadIdx.x & 63;
    float s = (lane < 32) ? Zbuf[wid * 32 + lane] : 0.f;
#pragma unroll
    for (int off = 32; off > 0; off >>= 1) s += __shfl_down(s, off, 64);
    if (lane == 0) Z[wid] = s;
}

// ---------------------------------------------------------------------------
extern "C" void kernel_launch(void* const* d_in, const int* in_sizes, int n_in,
                              void* d_out, int out_size, void* d_ws, size_t ws_size,
                              hipStream_t stream) {
    const float* x     = (const float*)d_in[0];
    const float* w_top = (const float*)d_in[1];
    const float* b_top = (const float*)d_in[2];
    const float* w_cen = (const float*)d_in[3];
    const float* b_cen = (const float*)d_in[4];
    const float* w_bot = (const float*)d_in[5];
    const float* b_bot = (const float*)d_in[6];
    const float* w_out = (const float*)d_in[7];
    const float* b_out = (const float*)d_in[8];

    char* W = (char*)d_ws;
    short* xp   = (short*)(W);               // 17,842,176 B (also reused as yp)
    short* xt   = (short*)(W + 17842176);    //  2,097,152
    short* xc   = (short*)(W + 19939328);    //  2,097,152
    short* wtb  = (short*)(W + 22036480);    //     65,536
    short* wcb  = (short*)(W + 22102016);    //     65,536
    short* wbT  = (short*)(W + 22167552);    //  4,718,592
    short* woT  = (short*)(W + 26886144);    //  4,718,592
    short* xbc  = (short*)(W + 31604736);    // 16,777,216
    float* O    = (float*)(W + 48381952);    // 33,554,432 (unscaled PV output)
    float* Z    = (float*)(W + 81936384);    //        512
    float* Zbuf = (float*)(W + 81936896);    //     16,384 (uses 128 floats)

    k_fill0<<<4356, 256, 0, stream>>>((uint4*)xp);           // zero padded buffer
    k_wpc<<<dim3(32, 2), 256, 0, stream>>>(w_top, w_cen, wtb, wcb);
    k_w9<<<dim3(512, 2, 2), 256, 0, stream>>>(w_bot, w_out, wbT, woT);
    k_padT<false><<<dim3(64, 8, BATCH), 256, 0, stream>>>(x, nullptr, nullptr, xp);
    k_qk<<<dim3(64, 8), 256, 0, stream>>>(xp, wtb, wcb, b_top, b_cen, xt, xc);
    k_conv<false><<<dim3(32, 4, BATCH), 256, 0, stream>>>(xp, wbT, b_bot, xbc);
    k_fused<<<dim3(256), 512, 0, stream>>>(xc, xt, xbc, O, Zbuf);
    k_redz<<<1, 256, 0, stream>>>(Zbuf, Z);
    k_padT<true><<<dim3(64, 8, BATCH), 256, 0, stream>>>(x, O, Z, xp);  // y -> xp
    k_conv<true><<<dim3(32, 4, BATCH), 256, 0, stream>>>(xp, woT, b_out, (float*)d_out);
}